// Round 3
// baseline (162.938 us; speedup 1.0000x reference)
//
#include <hip/hip_runtime.h>
#include <hip/hip_bf16.h>

#define T_WORDS 800000
#define S_SENT 2048
#define DIN 256
#define DOUT 128
#define CHUNK 32
#define BLK 512

typedef short bf16x8 __attribute__((ext_vector_type(8)));
typedef float f32x4 __attribute__((ext_vector_type(4)));

__device__ __forceinline__ unsigned short f2bf(float f) {
  unsigned int u = __builtin_bit_cast(unsigned int, f);
  u += 0x7fffu + ((u >> 16) & 1u);   // round-to-nearest-even
  return (unsigned short)(u >> 16);
}

// Prep: weight f32 -> bf16 into ws; sentence start offsets from sorted seg_ids.
__global__ void prep_kernel(const float* __restrict__ weight,
                            const int* __restrict__ seg,
                            unsigned short* __restrict__ wsB,
                            int* __restrict__ starts) {
  int tid = blockIdx.x * blockDim.x + threadIdx.x;
  int stride = gridDim.x * blockDim.x;
  for (int j = tid; j < DOUT * DIN; j += stride)
    wsB[j] = f2bf(weight[j]);
  for (int j = tid; j < T_WORDS; j += stride) {
    if (j == 0) {
      starts[seg[0]] = 0;
    } else {
      int s1 = seg[j], s0 = seg[j - 1];
      if (s1 != s0) starts[s1] = j;
    }
  }
}

// One block per sentence. 8 waves; wave w owns output cols [16w, 16w+16).
// 32-row chunks, double-buffered LDS, 2-deep register prefetch with counted
// vmcnt (lgkm-only barrier keeps global loads in flight across chunks).
__global__ __launch_bounds__(BLK, 4) void pool_kernel(
    const float* __restrict__ tokens,
    const float* __restrict__ bias,
    const unsigned short* __restrict__ wsB,
    const int* __restrict__ starts,
    const int* __restrict__ sent_batch,
    const int* __restrict__ sent_pos,
    float* __restrict__ out) {
  __shared__ alignas(16) unsigned short Alds[2][CHUNK * DIN];  // 2 x 16 KB

  const int s = blockIdx.x;
  const int start = starts[s];
  const int end = (s == S_SENT - 1) ? T_WORDS : starts[s + 1];
  const int lane = (int)(threadIdx.x & 63);
  const int wv = (int)(threadIdx.x >> 6);

  // B fragment: lane holds col = 16*wv + (lane&15), k = 8*(lane>>4)+j (+32*kk).
  bf16x8 bfrag[8];
  {
    const int col = 16 * wv + (lane & 15);
    const unsigned short* wrow = wsB + col * DIN + 8 * (lane >> 4);
#pragma unroll
    for (int kk = 0; kk < 8; ++kk)
      bfrag[kk] = *(const bf16x8*)(wrow + 32 * kk);
  }

  // Staging map: thread t covers row = t>>4 (0..31), f32 cols [16*(t&15), +16).
  const int srow = (int)(threadIdx.x >> 4);
  const int skseg = (int)(threadIdx.x & 15);
  const int sw = (srow & 7) << 3;
  const int sidx0 = srow * DIN + skseg * 16;

  float runmax = -INFINITY;
  float4 pA0, pA1, pA2, pA3, pB0, pB1, pB2, pB3;

#define ISSUE(P0, P1, P2, P3, WBASE)                                          \
  {                                                                           \
    int word = (WBASE) + srow;                                                \
    if (word < end) {                                                         \
      const float4* src =                                                     \
          (const float4*)(tokens + (size_t)word * DIN + skseg * 16);          \
      P0 = src[0]; P1 = src[1]; P2 = src[2]; P3 = src[3];                     \
    }                                                                         \
  }

#define WRITE(P0, P1, P2, P3, BUF)                                            \
  {                                                                           \
    bf16x8 v0, v1;                                                            \
    v0[0] = (short)f2bf(P0.x); v0[1] = (short)f2bf(P0.y);                     \
    v0[2] = (short)f2bf(P0.z); v0[3] = (short)f2bf(P0.w);                     \
    v0[4] = (short)f2bf(P1.x); v0[5] = (short)f2bf(P1.y);                     \
    v0[6] = (short)f2bf(P1.z); v0[7] = (short)f2bf(P1.w);                     \
    v1[0] = (short)f2bf(P2.x); v1[1] = (short)f2bf(P2.y);                     \
    v1[2] = (short)f2bf(P2.z); v1[3] = (short)f2bf(P2.w);                     \
    v1[4] = (short)f2bf(P3.x); v1[5] = (short)f2bf(P3.y);                     \
    v1[6] = (short)f2bf(P3.z); v1[7] = (short)f2bf(P3.w);                     \
    *(bf16x8*)&Alds[BUF][sidx0 ^ sw] = v0;                                    \
    *(bf16x8*)&Alds[BUF][(sidx0 + 8) ^ sw] = v1;                              \
  }

#define COMPUTE(BUF, WBASE)                                                   \
  {                                                                           \
    _Pragma("unroll") for (int m = 0; m < 2; ++m) {                           \
      f32x4 acc = (f32x4){0.f, 0.f, 0.f, 0.f};                                \
      const int arow = 16 * m + (lane & 15);                                  \
      const int abase = arow * DIN + 8 * (lane >> 4);                         \
      const int axor = (lane & 7) << 3;                                       \
      _Pragma("unroll") for (int kk = 0; kk < 8; ++kk) {                      \
        bf16x8 a = *(const bf16x8*)&Alds[BUF][(abase + 32 * kk) ^ axor];      \
        acc = __builtin_amdgcn_mfma_f32_16x16x32_bf16(a, bfrag[kk], acc,      \
                                                      0, 0, 0);               \
      }                                                                       \
      const int w0 = (WBASE) + 16 * m + 4 * (lane >> 4);                      \
      _Pragma("unroll") for (int r = 0; r < 4; ++r) {                         \
        if (w0 + r < end) runmax = fmaxf(runmax, acc[r]);                     \
      }                                                                       \
    }                                                                         \
  }

  // lgkm-only barrier: ds_writes visible to all waves, global loads (vmcnt)
  // stay in flight. (__syncthreads would drain vmcnt(0) — m97 stall.)
#define BAR()                                                                 \
  {                                                                           \
    asm volatile("s_waitcnt lgkmcnt(0)" ::: "memory");                        \
    __builtin_amdgcn_s_barrier();                                             \
  }

  const int nch = (end - start + CHUNK - 1) / CHUNK;

  // Prologue: chunks 0 and 1 in flight; chunk 0 staged to buf0.
  ISSUE(pA0, pA1, pA2, pA3, start)
  if (nch > 1) ISSUE(pB0, pB1, pB2, pB3, start + CHUNK)
  WRITE(pA0, pA1, pA2, pA3, 0)
  BAR()

  int c = 0;
  while (true) {
    // even chunk -> buf0, prefetch regs A free for chunk c+2
    COMPUTE(0, start + c * CHUNK)
    if (c + 2 < nch) ISSUE(pA0, pA1, pA2, pA3, start + (c + 2) * CHUNK)
    if (c + 1 < nch) WRITE(pB0, pB1, pB2, pB3, 1)   // waits vmcnt(4): A in flight
    BAR()
    if (++c >= nch) break;

    // odd chunk -> buf1
    COMPUTE(1, start + c * CHUNK)
    if (c + 2 < nch) ISSUE(pB0, pB1, pB2, pB3, start + (c + 2) * CHUNK)
    if (c + 1 < nch) WRITE(pA0, pA1, pA2, pA3, 0)
    BAR()
    if (++c >= nch) break;
  }

  // Reduce across the 4 row-groups (lanes differing in bits 4,5).
  runmax = fmaxf(runmax, __shfl_xor(runmax, 16, 64));
  runmax = fmaxf(runmax, __shfl_xor(runmax, 32, 64));

  if (lane < 16) {
    const int sb = sent_batch[s], sp = sent_pos[s];
    float* o = out + ((size_t)sb * 64 + sp) * DOUT;
    const int c0 = 16 * wv + lane;
    o[c0] = runmax + bias[c0];
  }
}

extern "C" void kernel_launch(void* const* d_in, const int* in_sizes, int n_in,
                              void* d_out, int out_size, void* d_ws, size_t ws_size,
                              hipStream_t stream) {
  const float* tokens = (const float*)d_in[0];
  const float* weight = (const float*)d_in[1];
  const float* bias   = (const float*)d_in[2];
  const int* seg      = (const int*)d_in[3];
  const int* sbatch   = (const int*)d_in[4];
  const int* spos     = (const int*)d_in[5];
  float* out = (float*)d_out;

  unsigned short* wsB = (unsigned short*)d_ws;                    // 64 KB bf16 weight
  int* starts = (int*)((char*)d_ws + DOUT * DIN * sizeof(unsigned short));  // 8 KB

  prep_kernel<<<512, 256, 0, stream>>>(weight, seg, wsB, starts);
  pool_kernel<<<S_SENT, BLK, 0, stream>>>(tokens, bias, wsB, starts, sbatch, spos, out);
}

// Round 5
// 160.811 us; speedup vs baseline: 1.0132x; 1.0132x over previous
//
#include <hip/hip_runtime.h>
#include <hip/hip_bf16.h>

#define T_WORDS 800000
#define S_SENT 2048
#define DIN 256
#define DOUT 128
#define CHUNK 32

typedef short bf16x8 __attribute__((ext_vector_type(8)));
typedef float f32x4 __attribute__((ext_vector_type(4)));

union V16 { bf16x8 v; unsigned int u[4]; };

__device__ __forceinline__ unsigned int pk2(float lo, float hi) {
  // paired _rn cast lowers to v_cvt_pk_bf16_f32 (RNE)
  __hip_bfloat162 h = __float22bfloat162_rn(float2{lo, hi});
  unsigned int u;
  __builtin_memcpy(&u, &h, sizeof(u));
  return u;
}

__device__ __forceinline__ unsigned short f2bf(float f) {
  unsigned int u = __builtin_bit_cast(unsigned int, f);
  u += 0x7fffu + ((u >> 16) & 1u);
  return (unsigned short)(u >> 16);
}

// Prep: weight f32 -> bf16 into ws; sentence start offsets from sorted seg_ids.
__global__ void prep_kernel(const float* __restrict__ weight,
                            const int* __restrict__ seg,
                            unsigned short* __restrict__ wsB,
                            int* __restrict__ starts) {
  int tid = blockIdx.x * blockDim.x + threadIdx.x;
  int stride = gridDim.x * blockDim.x;
  for (int j = tid; j < DOUT * DIN; j += stride)
    wsB[j] = f2bf(weight[j]);
  for (int j = tid; j < T_WORDS; j += stride) {
    if (j == 0) {
      starts[seg[0]] = 0;
    } else {
      int s1 = seg[j], s0 = seg[j - 1];
      if (s1 != s0) starts[s1] = j;
    }
  }
}

// One block per sentence. 4 waves; wave w owns output cols [32w, 32w+32).
// 32-row chunks, double-buffered LDS. Rotated pipeline per iteration:
//   WRITE(c+1 from pf) -> ISSUE(pf, c+2) -> COMPUTE(c) -> lgkm-barrier
// so the vmcnt wait in WRITE lands a full iteration after the loads issued.
__global__ __launch_bounds__(256, 3) void pool_kernel(
    const float* __restrict__ tokens,
    const float* __restrict__ bias,
    const unsigned short* __restrict__ wsB,
    const int* __restrict__ starts,
    const int* __restrict__ sent_batch,
    const int* __restrict__ sent_pos,
    float* __restrict__ out) {
  __shared__ alignas(16) unsigned short Alds[2][CHUNK * DIN];  // 2 x 16 KB

  const int s = blockIdx.x;
  const int start = starts[s];
  const int end = (s == S_SENT - 1) ? T_WORDS : starts[s + 1];
  const int lane = (int)(threadIdx.x & 63);
  const int wv = (int)(threadIdx.x >> 6);

  // B fragments: lane holds col = 32*wv + 16n + (lane&15), k = 8*(lane>>4)+j.
  bf16x8 bfrag[2][8];
#pragma unroll
  for (int n = 0; n < 2; ++n) {
    const int col = 32 * wv + 16 * n + (lane & 15);
    const unsigned short* wrow = wsB + col * DIN + 8 * (lane >> 4);
#pragma unroll
    for (int kk = 0; kk < 8; ++kk)
      bfrag[n][kk] = *(const bf16x8*)(wrow + 32 * kk);
  }

  // Staging map: thread t, iter it covers row = (t>>5) + 8*it,
  // f32 cols [8*(t&31), +8) -> 2 float4 loads (32B contiguous per thread).
  const int srow0 = (int)(threadIdx.x >> 5);
  const int sk8 = (int)(threadIdx.x & 31);

  float runmax0 = -INFINITY, runmax1 = -INFINITY;
  float4 pf[4][2];

#define ISSUE(WBASE)                                                          \
  {                                                                           \
    _Pragma("unroll") for (int it = 0; it < 4; ++it) {                        \
      int word = (WBASE) + srow0 + 8 * it;                                    \
      if (word < end) {                                                       \
        const float4* src =                                                   \
            (const float4*)(tokens + (size_t)word * DIN + sk8 * 8);           \
        pf[it][0] = src[0];                                                   \
        pf[it][1] = src[1];                                                   \
      }                                                                       \
    }                                                                         \
  }

  // OOB rows staged as bf16 -inf (0xFF80) so the fold is unconditional.
#define WRITE(WBASE, BUF)                                                     \
  {                                                                           \
    _Pragma("unroll") for (int it = 0; it < 4; ++it) {                        \
      int row = srow0 + 8 * it;                                               \
      bool valid = (WBASE) + row < end;                                       \
      V16 w;                                                                  \
      w.u[0] = valid ? pk2(pf[it][0].x, pf[it][0].y) : 0xFF80FF80u;           \
      w.u[1] = valid ? pk2(pf[it][0].z, pf[it][0].w) : 0xFF80FF80u;           \
      w.u[2] = valid ? pk2(pf[it][1].x, pf[it][1].y) : 0xFF80FF80u;           \
      w.u[3] = valid ? pk2(pf[it][1].z, pf[it][1].w) : 0xFF80FF80u;           \
      int idx = (row * DIN + sk8 * 8) ^ ((row & 7) << 3);                     \
      *(bf16x8*)&Alds[BUF][idx] = w.v;                                        \
    }                                                                         \
  }

#define COMPUTE(BUF)                                                          \
  {                                                                           \
    _Pragma("unroll") for (int m = 0; m < 2; ++m) {                           \
      f32x4 acc0 = (f32x4){0.f, 0.f, 0.f, 0.f};                               \
      f32x4 acc1 = (f32x4){0.f, 0.f, 0.f, 0.f};                               \
      const int arow = 16 * m + (lane & 15);                                  \
      const int abase = arow * DIN + 8 * (lane >> 4);                         \
      const int axor = (lane & 7) << 3;                                       \
      _Pragma("unroll") for (int kk = 0; kk < 8; ++kk) {                      \
        bf16x8 a = *(const bf16x8*)&Alds[BUF][(abase + 32 * kk) ^ axor];      \
        acc0 = __builtin_amdgcn_mfma_f32_16x16x32_bf16(a, bfrag[0][kk], acc0, \
                                                       0, 0, 0);              \
        acc1 = __builtin_amdgcn_mfma_f32_16x16x32_bf16(a, bfrag[1][kk], acc1, \
                                                       0, 0, 0);              \
      }                                                                       \
      runmax0 = fmaxf(runmax0, fmaxf(fmaxf(acc0[0], acc0[1]),                 \
                                     fmaxf(acc0[2], acc0[3])));               \
      runmax1 = fmaxf(runmax1, fmaxf(fmaxf(acc1[0], acc1[1]),                 \
                                     fmaxf(acc1[2], acc1[3])));               \
    }                                                                         \
  }

  // lgkm-only barrier: ds ops drained, global loads (vmcnt) stay in flight.
#define BAR()                                                                 \
  {                                                                           \
    asm volatile("s_waitcnt lgkmcnt(0)" ::: "memory");                        \
    __builtin_amdgcn_s_barrier();                                             \
  }

  const int nch = (end - start + CHUNK - 1) / CHUNK;

  // Prologue: chunk 0 -> buf0 (one cold vmcnt stall), chunk 1 loads in flight.
  ISSUE(start)
  WRITE(start, 0)
  if (nch > 1) ISSUE(start + CHUNK)
  BAR()

  int c = 0;
  while (true) {
    int wb = start + c * CHUNK;
    // even chunk: compute buf0; stage c+1 -> buf1; issue c+2
    if (c + 1 < nch) WRITE(wb + CHUNK, 1)
    if (c + 2 < nch) ISSUE(wb + 2 * CHUNK)
    COMPUTE(0)
    BAR()
    if (++c >= nch) break;

    wb = start + c * CHUNK;
    // odd chunk: compute buf1; stage c+1 -> buf0; issue c+2
    if (c + 1 < nch) WRITE(wb + CHUNK, 0)
    if (c + 2 < nch) ISSUE(wb + 2 * CHUNK)
    COMPUTE(1)
    BAR()
    if (++c >= nch) break;
  }

  // Reduce across the 4 row-groups (lanes differing in bits 4,5).
  runmax0 = fmaxf(runmax0, __shfl_xor(runmax0, 16, 64));
  runmax0 = fmaxf(runmax0, __shfl_xor(runmax0, 32, 64));
  runmax1 = fmaxf(runmax1, __shfl_xor(runmax1, 16, 64));
  runmax1 = fmaxf(runmax1, __shfl_xor(runmax1, 32, 64));

  if (lane < 16) {
    const int sb = sent_batch[s], sp = sent_pos[s];
    float* o = out + ((size_t)sb * 64 + sp) * DOUT;
    const int c0 = 32 * wv + lane;
    o[c0] = runmax0 + bias[c0];
    o[c0 + 16] = runmax1 + bias[c0 + 16];
  }
}

extern "C" void kernel_launch(void* const* d_in, const int* in_sizes, int n_in,
                              void* d_out, int out_size, void* d_ws, size_t ws_size,
                              hipStream_t stream) {
  const float* tokens = (const float*)d_in[0];
  const float* weight = (const float*)d_in[1];
  const float* bias   = (const float*)d_in[2];
  const int* seg      = (const int*)d_in[3];
  const int* sbatch   = (const int*)d_in[4];
  const int* spos     = (const int*)d_in[5];
  float* out = (float*)d_out;

  unsigned short* wsB = (unsigned short*)d_ws;                    // 64 KB bf16 weight
  int* starts = (int*)((char*)d_ws + DOUT * DIN * sizeof(unsigned short));  // 8 KB

  prep_kernel<<<512, 256, 0, stream>>>(weight, seg, wsB, starts);
  pool_kernel<<<S_SENT, 256, 0, stream>>>(tokens, bias, wsB, starts, sbatch, spos, out);
}